// Round 9
// baseline (171.193 us; speedup 1.0000x reference)
//
#include <hip/hip_runtime.h>
#include <hip/hip_bf16.h>

// Problem constants
constexpr int Bb  = 8;
constexpr int Ss  = 2048;
constexpr int Ee  = 128;
constexpr int Hh  = 8;
constexpr int HSs = 16;
constexpr int QKVSZ = Bb * Hh * Ss * HSs;  // 2,097,152 elements per tensor

typedef _Float16 f16;
typedef __attribute__((ext_vector_type(8)))  _Float16 f16x8;   // 8 f16 = 4 VGPRs
typedef __attribute__((ext_vector_type(16))) float f32x16;

constexpr float QSCALE = 5.770780163555854f;  // 4 * log2(e); folded into stored k

// RTZ packed fp32x2 -> fp16x2
__device__ __forceinline__ unsigned pack_rtz(float lo, float hi) {
    union { __fp16 __attribute__((ext_vector_type(2))) h; unsigned u; } c;
    c.h = __builtin_amdgcn_cvt_pkrtz(lo, hi);
    return c.u;
}
// RNE pair pack
__device__ __forceinline__ unsigned pack_rne(float lo, float hi) {
    union { __attribute__((ext_vector_type(2))) _Float16 h; unsigned u; } c;
    c.h[0] = (f16)lo; c.h[1] = (f16)hi;
    return c.u;
}
// 8 consecutive global floats -> f16x8 (RNE)
__device__ __forceinline__ f16x8 cvt8(const float* p) {
    float4 a = *(const float4*)p;
    float4 b = *(const float4*)(p + 4);
    f16x8 r;
    r[0] = (f16)a.x; r[1] = (f16)a.y; r[2] = (f16)a.z; r[3] = (f16)a.w;
    r[4] = (f16)b.x; r[5] = (f16)b.y; r[6] = (f16)b.z; r[7] = (f16)b.w;
    return r;
}

// ---------------------------------------------------------------------------
// Kernel A: Q/K/V projection. fp32 in (x, W) -> f16 q/k/v out (preps fused).
// Grid (128 M-tiles, 3 mats), 4 waves. X tile staged fp32->f16 via LDS with
// COALESCED float4 loads; padded rows (136 f16) keep ds_read ~4-way max.
// Wave owns 32 rows; A-frags loaded once from LDS, reused over 4 ch groups.
// k scaled by QSCALE pre-round; v stored frag-swizzled for attn staging:
//   (s,d) -> bh*32768 + (s>>6)*1024 + ((s>>4)&3)*256 + ((s>>3)&1)*128 + d*8 + (s&7)
// 32x32x16 layouts: A[m=lane&31][k=8h+j], B[k=8h+j][n=lane&31],
// C/D[row=(r&3)+8(r>>2)+4h][col=lane&31].
// ---------------------------------------------------------------------------
__global__ __launch_bounds__(256) void qkv_kernel(
    const float* __restrict__ x,  const float* __restrict__ Wq,
    const float* __restrict__ Wk, const float* __restrict__ Wv,
    f16* __restrict__ qo, f16* __restrict__ ko, f16* __restrict__ vo)
{
    constexpr int LDW = 136;                      // padded LDS row (f16)
    __shared__ __align__(16) f16 Xs[128 * LDW];   // 34 KB

    const int mat = blockIdx.y;                   // 0=q,1=k,2=v
    const float* W = (mat == 0) ? Wq : ((mat == 1) ? Wk : Wv);
    const int rowbase = blockIdx.x * 128;

    // stage X tile: coalesced fp32 reads, cvt, LDS write
    for (int idx = threadIdx.x; idx < 128 * 32; idx += 256) {
        const int r = idx >> 5, cp = idx & 31;    // cp = float4 index in row
        float4 v = *(const float4*)(x + (size_t)(rowbase + r) * Ee + cp * 4);
        union { f16 h[4]; uint2 u; } c;
        c.h[0] = (f16)v.x; c.h[1] = (f16)v.y; c.h[2] = (f16)v.z; c.h[3] = (f16)v.w;
        *(uint2*)&Xs[r * LDW + cp * 4] = c.u;
    }
    __syncthreads();

    const int wv_ = threadIdx.x >> 6, lane = threadIdx.x & 63;
    const int h = lane >> 5, n31 = lane & 31;
    const int rb2 = rowbase + wv_ * 32;

    f16x8 A[8];
#pragma unroll
    for (int t = 0; t < 8; ++t)
        A[t] = *(const f16x8*)&Xs[(wv_ * 32 + n31) * LDW + 16 * t + 8 * h];

    f16* dst = (mat == 0) ? qo : ((mat == 1) ? ko : vo);
    const float scale = (mat == 1) ? QSCALE : 1.f;

#pragma unroll
    for (int g = 0; g < 4; ++g) {
        const int c = g * 32 + n31;               // channel = head*16+d
        const float* wr = W + (size_t)c * Ee + 8 * h;
        f32x16 acc = {};
#pragma unroll
        for (int t = 0; t < 8; ++t)
            acc = __builtin_amdgcn_mfma_f32_32x32x16_f16(A[t], cvt8(wr + 16 * t), acc, 0, 0, 0);

        const int head = c >> 4, d = c & 15;
#pragma unroll
        for (int r = 0; r < 16; ++r) {
            const int R = rb2 + (r & 3) + 8 * (r >> 2) + 4 * h;
            const int b = R >> 11, s = R & 2047;
            const int bh = b * Hh + head;
            f16 val = (f16)(acc[r] * scale);
            if (mat == 2) {
                dst[(size_t)bh * 32768 + (s >> 6) * 1024 + ((s >> 4) & 3) * 256
                    + ((s >> 3) & 1) * 128 + d * 8 + (s & 7)] = val;
            } else {
                dst[((size_t)bh * Ss + s) * HSs + d] = val;
            }
        }
    }
}

// ---------------------------------------------------------------------------
// Kernel B: MFMA flash attention, f16 I/O, 64-key chunks, DOUBLE-BUFFERED
// K/V staging -> one __syncthreads per chunk (was two).
// Block = 4 waves, same (b,h); wave owns 32 queries.
// Softmax state lane-local (q = lane&31); P^T C->B relayout via shfl_xor 32.
// XCD swizzle: 16 q-blocks of each bh land on one XCD (K/V L2-resident).
// ---------------------------------------------------------------------------
__device__ __forceinline__ void cb_exchange(const unsigned* pw, int h,
                                            f16x8& Blo, f16x8& Bhi) {
    unsigned exa = (unsigned)__shfl_xor((int)(h ? pw[0] : pw[2]), 32, 64);
    unsigned exb = (unsigned)__shfl_xor((int)(h ? pw[1] : pw[3]), 32, 64);
    unsigned exc = (unsigned)__shfl_xor((int)(h ? pw[4] : pw[6]), 32, 64);
    unsigned exd = (unsigned)__shfl_xor((int)(h ? pw[5] : pw[7]), 32, 64);
    union { unsigned u[4]; f16x8 v; } B1, B2;
    if (h == 0) {
        B1.u[0] = pw[0]; B1.u[1] = pw[1]; B1.u[2] = exa; B1.u[3] = exb;
        B2.u[0] = pw[4]; B2.u[1] = pw[5]; B2.u[2] = exc; B2.u[3] = exd;
    } else {
        B1.u[0] = exa; B1.u[1] = exb; B1.u[2] = pw[2]; B1.u[3] = pw[3];
        B2.u[0] = exc; B2.u[1] = exd; B2.u[2] = pw[6]; B2.u[3] = pw[7];
    }
    Blo = B1.v; Bhi = B2.v;
}

__global__ __launch_bounds__(256) void attn_kernel(
    const f16* __restrict__ qg, const f16* __restrict__ kg,
    const f16* __restrict__ vg, f16* __restrict__ og)
{
    __shared__ __align__(16) f16 Ks[2][64 * 24];   // dbuf [key][d], 48B rows, 6KB
    __shared__ __align__(16) f16 Vf[2][2048];      // dbuf A-frag order, 8KB

    // XCD-aware decode: bh = xcd*8 + (w>>4), qblk = w&15
    const int blk  = blockIdx.x;
    const int w_   = blk >> 3;
    const int bh   = (blk & 7) * 8 + (w_ >> 4);
    const int qblk = w_ & 15;
    const int wv_  = threadIdx.x >> 6;
    const int lane = threadIdx.x & 63;
    const int h    = lane >> 5;
    const int q31  = lane & 31;
    const int qbase = qblk * 128 + wv_ * 32;

    // zero Vf pad slots (m>=16) in BOTH buffers once
    {
        const int i = threadIdx.x;                 // 256 x 16B = 4KB of pads
        const int b = i >> 7, rem = i & 127;
        const int g = rem >> 5, hh = (rem >> 4) & 1, sub = i & 15;
        *(uint4*)&Vf[b][g * 512 + hh * 256 + 128 + sub * 8] = (uint4){0, 0, 0, 0};
    }

    // Q B-frag (QSCALE folded into k)
    const f16x8 qf = *(const f16x8*)(qg + ((size_t)bh * Ss + qbase + q31) * HSs + 8 * h);

    // staging: thread t<128 copies 16B of K, t>=128 copies 16B of V (frag order)
    const bool isK = threadIdx.x < 128;
    const int  i   = threadIdx.x & 127;
    const f16* gsrc = isK ? (kg + (size_t)bh * Ss * HSs + i * 8)
                          : (vg + (size_t)bh * 32768 + i * 8);
    const int koff = (i >> 1) * 24 + (i & 1) * 8;
    const int voff = (i >> 5) * 512 + ((i >> 4) & 1) * 256 + (i & 15) * 8;
    f16x8 sreg = *(const f16x8*)gsrc;

    // pre-write chunk 0 into buffer 0; prefetch chunk 1
    if (isK) *(f16x8*)&Ks[0][koff] = sreg; else *(f16x8*)&Vf[0][voff] = sreg;
    gsrc += 1024; sreg = *(const f16x8*)gsrc;

    f32x16 acc = {};
    const f32x16 z16 = {};
    float m = -1e30f, l = 0.f;

    for (int it = 0; it < Ss / 64; ++it) {
        __syncthreads();   // buf[it&1] complete; prior readers of buf[(it+1)&1] done
        if (it < Ss / 64 - 1) {
            const int nb = (it + 1) & 1;
            if (isK) *(f16x8*)&Ks[nb][koff] = sreg; else *(f16x8*)&Vf[nb][voff] = sreg;
            gsrc += 1024; sreg = *(const f16x8*)gsrc;   // last one over-reads ws, unused
        }
        const int cb = it & 1;

        // S^T = K x Q^T for key groups 0..31, 32..63
        f16x8 ka0 = *(const f16x8*)&Ks[cb][q31 * 24 + 8 * h];
        f16x8 ka1 = *(const f16x8*)&Ks[cb][(32 + q31) * 24 + 8 * h];
        f32x16 st0 = __builtin_amdgcn_mfma_f32_32x32x16_f16(ka0, qf, z16, 0, 0, 0);
        f32x16 st1 = __builtin_amdgcn_mfma_f32_32x32x16_f16(ka1, qf, z16, 0, 0, 0);

        // online softmax over 64 keys (in-lane trees + one xor32 each)
        float mx = st0[0];
#pragma unroll
        for (int t = 1; t < 16; ++t) mx = fmaxf(mx, st0[t]);
#pragma unroll
        for (int t = 0; t < 16; ++t) mx = fmaxf(mx, st1[t]);
        mx = fmaxf(mx, __shfl_xor(mx, 32, 64));
        const float mnew = fmaxf(m, mx);
        const float corr = __builtin_amdgcn_exp2f(m - mnew);
        float p0[16], p1[16];
        float rs = 0.f;
#pragma unroll
        for (int t = 0; t < 16; ++t) { p0[t] = __builtin_amdgcn_exp2f(st0[t] - mnew); rs += p0[t]; }
#pragma unroll
        for (int t = 0; t < 16; ++t) { p1[t] = __builtin_amdgcn_exp2f(st1[t] - mnew); rs += p1[t]; }
        rs += __shfl_xor(rs, 32, 64);
        l = l * corr + rs;
#pragma unroll
        for (int r = 0; r < 8; ++r) acc[r] *= corr;   // only d<16 regs live
        m = mnew;

        // pack P^T pairs, relayout C->B
        unsigned pw0[8], pw1[8];
#pragma unroll
        for (int r = 0; r < 8; ++r) pw0[r] = pack_rtz(p0[2 * r], p0[2 * r + 1]);
#pragma unroll
        for (int r = 0; r < 8; ++r) pw1[r] = pack_rtz(p1[2 * r], p1[2 * r + 1]);
        f16x8 B1, B2, B3, B4;
        cb_exchange(pw0, h, B1, B2);
        cb_exchange(pw1, h, B3, B4);

        // O^T += V^T x P^T over 4 key groups (A-frags direct from Vf)
        f16x8 va0 = *(const f16x8*)&Vf[cb][0 * 512 + lane * 8];
        f16x8 va1 = *(const f16x8*)&Vf[cb][1 * 512 + lane * 8];
        f16x8 va2 = *(const f16x8*)&Vf[cb][2 * 512 + lane * 8];
        f16x8 va3 = *(const f16x8*)&Vf[cb][3 * 512 + lane * 8];
        acc = __builtin_amdgcn_mfma_f32_32x32x16_f16(va0, B1, acc, 0, 0, 0);
        acc = __builtin_amdgcn_mfma_f32_32x32x16_f16(va1, B2, acc, 0, 0, 0);
        acc = __builtin_amdgcn_mfma_f32_32x32x16_f16(va2, B3, acc, 0, 0, 0);
        acc = __builtin_amdgcn_mfma_f32_32x32x16_f16(va3, B4, acc, 0, 0, 0);
    }

    // write O as f16: lane q31 owns d = {4h..4h+3} (regs0-3), {8+4h..} (regs4-7)
    const float inv = 1.f / l;
    const int b = bh >> 3, head = bh & 7;
    f16* op = og + ((size_t)b * Ss + qbase + q31) * Ee + head * HSs;
    uint2 lo = { pack_rne(acc[0] * inv, acc[1] * inv), pack_rne(acc[2] * inv, acc[3] * inv) };
    uint2 hi = { pack_rne(acc[4] * inv, acc[5] * inv), pack_rne(acc[6] * inv, acc[7] * inv) };
    *(uint2*)(op + 4 * h)     = lo;
    *(uint2*)(op + 8 + 4 * h) = hi;
}

// ---------------------------------------------------------------------------
// Kernel C: output projection. O (f16) staged via LDS coalesced; Wp fp32 +
// inline cvt; fp32 out + bias. Grid 256 blocks x 2 waves; wave = 32 rows,
// 4 channel groups.
// ---------------------------------------------------------------------------
__global__ __launch_bounds__(128) void proj_kernel(
    const f16* __restrict__ oh, const float* __restrict__ Wp,
    const float* __restrict__ bp, float* __restrict__ out)
{
    constexpr int LDW = 136;
    __shared__ __align__(16) f16 Os[64 * LDW];    // 17 KB
    const int rowbase = blockIdx.x * 64;

    // stage O tile: coalesced b128 copies (already f16)
    for (int idx = threadIdx.x; idx < 64 * 16; idx += 128) {
        const int r = idx >> 4, cp = idx & 15;    // cp = f16x8 index in row
        *(f16x8*)&Os[r * LDW + cp * 8] =
            *(const f16x8*)(oh + (size_t)(rowbase + r) * Ee + cp * 8);
    }
    __syncthreads();

    const int wv_ = threadIdx.x >> 6, lane = threadIdx.x & 63;
    const int h = lane >> 5, n31 = lane & 31;
    const int rb2 = rowbase + wv_ * 32;

    f16x8 A[8];
#pragma unroll
    for (int t = 0; t < 8; ++t)
        A[t] = *(const f16x8*)&Os[(wv_ * 32 + n31) * LDW + 16 * t + 8 * h];

#pragma unroll
    for (int g = 0; g < 4; ++g) {
        const int e = g * 32 + n31;
        const float* wr = Wp + (size_t)e * Ee + 8 * h;
        f32x16 acc = {};
#pragma unroll
        for (int t = 0; t < 8; ++t)
            acc = __builtin_amdgcn_mfma_f32_32x32x16_f16(A[t], cvt8(wr + 16 * t), acc, 0, 0, 0);
        const float bias = bp[e];
#pragma unroll
        for (int r = 0; r < 16; ++r) {
            const int R = rb2 + (r & 3) + 8 * (r >> 2) + 4 * h;
            out[(size_t)R * Ee + e] = acc[r] + bias;
        }
    }
}

// ---------------------------------------------------------------------------
extern "C" void kernel_launch(void* const* d_in, const int* in_sizes, int n_in,
                              void* d_out, int out_size, void* d_ws, size_t ws_size,
                              hipStream_t stream)
{
    const float* x  = (const float*)d_in[0];
    const float* Wk = (const float*)d_in[1];
    const float* Wq = (const float*)d_in[2];
    const float* Wv = (const float*)d_in[3];
    const float* Wp = (const float*)d_in[4];
    const float* bp = (const float*)d_in[5];
    float* out = (float*)d_out;

    f16* ws = (f16*)d_ws;
    f16* qh = ws;                            // 2M f16
    f16* kh = ws + (size_t)QKVSZ;            // 2M
    f16* vh = ws + (size_t)2 * QKVSZ;        // 2M (frag-swizzled)
    f16* oh = ws + (size_t)3 * QKVSZ;        // 2M (also absorbs tail over-reads)

    qkv_kernel<<<dim3(Bb * Ss / 128, 3), 256, 0, stream>>>(x, Wq, Wk, Wv, qh, kh, vh);
    attn_kernel<<<Bb * Hh * (Ss / 128), 256, 0, stream>>>(qh, kh, vh, oh);
    proj_kernel<<<Bb * Ss / 64, 128, 0, stream>>>(oh, Wp, bp, out);
}

// Round 10
// 145.002 us; speedup vs baseline: 1.1806x; 1.1806x over previous
//
#include <hip/hip_runtime.h>
#include <hip/hip_bf16.h>

// Problem constants
constexpr int Bb  = 8;
constexpr int Ss  = 2048;
constexpr int Ee  = 128;
constexpr int Hh  = 8;
constexpr int HSs = 16;
constexpr int QKVSZ = Bb * Hh * Ss * HSs;  // 2,097,152 elements per tensor

typedef _Float16 f16;
typedef __attribute__((ext_vector_type(8)))  _Float16 f16x8;   // 8 f16 = 4 VGPRs
typedef __attribute__((ext_vector_type(16))) float f32x16;

constexpr float QSCALE = 5.770780163555854f;  // 4 * log2(e); folded into stored k

// RTZ packed fp32x2 -> fp16x2
__device__ __forceinline__ unsigned pack_rtz(float lo, float hi) {
    union { __fp16 __attribute__((ext_vector_type(2))) h; unsigned u; } c;
    c.h = __builtin_amdgcn_cvt_pkrtz(lo, hi);
    return c.u;
}
// RNE pair pack
__device__ __forceinline__ unsigned pack_rne(float lo, float hi) {
    union { __attribute__((ext_vector_type(2))) _Float16 h; unsigned u; } c;
    c.h[0] = (f16)lo; c.h[1] = (f16)hi;
    return c.u;
}

// ---------------------------------------------------------------------------
// prep_w: one-time fp32 -> f16 of all weights. wh = [wq|wk|wv|wp], 16K each.
// ---------------------------------------------------------------------------
__global__ __launch_bounds__(256) void prep_w(
    const float* __restrict__ Wq, const float* __restrict__ Wk,
    const float* __restrict__ Wv, const float* __restrict__ Wp,
    f16* __restrict__ wh)
{
    int i = (blockIdx.x * 256 + threadIdx.x) * 4;
    const float* src = (i < 16384) ? (Wq + i)
                     : (i < 32768) ? (Wk + i - 16384)
                     : (i < 49152) ? (Wv + i - 32768) : (Wp + i - 49152);
    float4 v = *(const float4*)src;
    union { f16 h[4]; uint2 u; } c;
    c.h[0] = (f16)v.x; c.h[1] = (f16)v.y; c.h[2] = (f16)v.z; c.h[3] = (f16)v.w;
    *(uint2*)(wh + i) = c.u;
}

// ---------------------------------------------------------------------------
// Kernel A: Q/K/V projection. 32-row tiles, grid (512, 3) = 6 blocks/CU.
// Block = 4 waves; wave = one 32-channel group (no g-loop). X tile staged
// fp32->f16 via LDS coalesced; W from pre-converted f16 (L1-hot).
// Output routed through an LDS transpose -> coalesced 16B stores.
// k scaled by QSCALE pre-round; v stored frag-swizzled for attn:
//   (s,d) -> bh*32768 + (s>>6)*1024 + ((s>>4)&3)*256 + ((s>>3)&1)*128 + d*8 + (s&7)
// 32x32x16 layouts: A[m=lane&31][k=8h+j], B[k=8h+j][n=lane&31],
// C/D[row=(r&3)+8(r>>2)+4h][col=lane&31].
// ---------------------------------------------------------------------------
__global__ __launch_bounds__(256) void qkv_kernel(
    const float* __restrict__ x, const f16* __restrict__ wh,
    f16* __restrict__ qo, f16* __restrict__ ko, f16* __restrict__ vo)
{
    constexpr int LDW = 136;                      // padded row (f16), b128-aligned
    __shared__ __align__(16) f16 Xs[32 * LDW];    // 8.7 KB; reused as out tile

    const int mat = blockIdx.y;                   // 0=q,1=k,2=v
    const int rowbase = blockIdx.x * 32;

    // stage X tile (32 x 128) fp32 -> f16, coalesced float4 reads
    for (int idx = threadIdx.x; idx < 32 * 32; idx += 256) {
        const int r = idx >> 5, cp = idx & 31;
        float4 v = *(const float4*)(x + (size_t)(rowbase + r) * Ee + cp * 4);
        union { f16 h[4]; uint2 u; } c;
        c.h[0] = (f16)v.x; c.h[1] = (f16)v.y; c.h[2] = (f16)v.z; c.h[3] = (f16)v.w;
        *(uint2*)&Xs[r * LDW + cp * 4] = c.u;
    }
    __syncthreads();

    const int wv_ = threadIdx.x >> 6, lane = threadIdx.x & 63;
    const int h = lane >> 5, n31 = lane & 31;

    f16x8 A[8];
#pragma unroll
    for (int t = 0; t < 8; ++t)
        A[t] = *(const f16x8*)&Xs[n31 * LDW + 16 * t + 8 * h];
    __syncthreads();                              // A in regs; Xs reusable

    const int c = wv_ * 32 + n31;                 // channel 0..127 = head*16+d
    const f16* wr = wh + mat * 16384 + (size_t)c * Ee + 8 * h;
    f32x16 acc = {};
#pragma unroll
    for (int t = 0; t < 8; ++t)
        acc = __builtin_amdgcn_mfma_f32_32x32x16_f16(A[t], *(const f16x8*)(wr + 16 * t), acc, 0, 0, 0);

    const float scale = (mat == 1) ? QSCALE : 1.f;
#pragma unroll
    for (int r = 0; r < 16; ++r) {
        const int row = (r & 3) + 8 * (r >> 2) + 4 * h;
        Xs[row * LDW + c] = (f16)(acc[r] * scale);
    }
    __syncthreads();

    // coalesced copy out of the 32x128 tile
    f16* dst = (mat == 0) ? qo : ((mat == 1) ? ko : vo);
    const int b = rowbase >> 11;
    const int s0 = rowbase & 2047;
    if (mat < 2) {
        for (int i = threadIdx.x; i < 512; i += 256) {
            const int head = i >> 6, rem = i & 63;
            const int s = rem >> 1, dh = rem & 1;
            const int bh = b * Hh + head;
            *(uint4*)(dst + ((size_t)bh * Ss + s0 + s) * HSs + dh * 8) =
                *(const uint4*)&Xs[s * LDW + head * HSs + dh * 8];
        }
    } else {
        for (int i = threadIdx.x; i < 512; i += 256) {
            const int head = i >> 6, rem = i & 63;
            const int d = rem & 15, ehalf = (rem >> 4) & 1, squart = rem >> 5;
            const int bh = b * Hh + head;
            union { f16 hv[8]; uint4 u; } pkt;
#pragma unroll
            for (int j = 0; j < 8; ++j) {
                const int ls = squart * 16 + ehalf * 8 + j;
                pkt.hv[j] = Xs[ls * LDW + head * HSs + d];
            }
            const size_t go = (size_t)bh * 32768 + (s0 >> 6) * 1024
                            + ((((s0 & 32) >> 4)) + squart) * 256 + ehalf * 128 + d * 8;
            *(uint4*)(dst + go) = pkt.u;
        }
    }
}

// ---------------------------------------------------------------------------
// Kernel B: MFMA flash attention, f16 I/O, 64-key chunks, dbuf staging,
// l accumulated BY THE PV MFMA via a ones-row at d=16 of V^T (acc[8]).
// Block = 4 waves, same (b,h); wave owns 32 queries; q = lane&31 lane-local.
// XCD swizzle: 16 q-blocks of each bh land on one XCD.
// ---------------------------------------------------------------------------
__device__ __forceinline__ void cb_exchange(const unsigned* pw, int h,
                                            f16x8& Blo, f16x8& Bhi) {
    unsigned exa = (unsigned)__shfl_xor((int)(h ? pw[0] : pw[2]), 32, 64);
    unsigned exb = (unsigned)__shfl_xor((int)(h ? pw[1] : pw[3]), 32, 64);
    unsigned exc = (unsigned)__shfl_xor((int)(h ? pw[4] : pw[6]), 32, 64);
    unsigned exd = (unsigned)__shfl_xor((int)(h ? pw[5] : pw[7]), 32, 64);
    union { unsigned u[4]; f16x8 v; } B1, B2;
    if (h == 0) {
        B1.u[0] = pw[0]; B1.u[1] = pw[1]; B1.u[2] = exa; B1.u[3] = exb;
        B2.u[0] = pw[4]; B2.u[1] = pw[5]; B2.u[2] = exc; B2.u[3] = exd;
    } else {
        B1.u[0] = exa; B1.u[1] = exb; B1.u[2] = pw[2]; B1.u[3] = pw[3];
        B2.u[0] = exc; B2.u[1] = exd; B2.u[2] = pw[6]; B2.u[3] = pw[7];
    }
    Blo = B1.v; Bhi = B2.v;
}

__global__ __launch_bounds__(256) void attn_kernel(
    const f16* __restrict__ qg, const f16* __restrict__ kg,
    const f16* __restrict__ vg, f16* __restrict__ og)
{
    __shared__ __align__(16) f16 Ks[2][64 * 24];   // dbuf [key][d], 48B rows, 6KB
    __shared__ __align__(16) f16 Vf[2][2048];      // dbuf A-frag order, 8KB

    const int blk  = blockIdx.x;
    const int w_   = blk >> 3;
    const int bh   = (blk & 7) * 8 + (w_ >> 4);
    const int qblk = w_ & 15;
    const int wv_  = threadIdx.x >> 6;
    const int lane = threadIdx.x & 63;
    const int h    = lane >> 5;
    const int q31  = lane & 31;
    const int qbase = qblk * 128 + wv_ * 32;

    // fill Vf pad rows (m>=16): zeros, EXCEPT m==16 row = ones (l-accumulator)
    {
        const int i = threadIdx.x;                 // 256 chunks of 16B
        const int bb = i >> 7, rem = i & 127;
        const int g = rem >> 5, hh = (rem >> 4) & 1, sub = rem & 15;
        const unsigned one2 = 0x3C003C00u;         // two f16 1.0
        uint4 val = (sub == 0) ? (uint4){one2, one2, one2, one2} : (uint4){0, 0, 0, 0};
        *(uint4*)&Vf[bb][g * 512 + hh * 256 + 128 + sub * 8] = val;
    }

    // Q B-frag (QSCALE folded into k)
    const f16x8 qf = *(const f16x8*)(qg + ((size_t)bh * Ss + qbase + q31) * HSs + 8 * h);

    // staging: t<128 copies 16B of K, t>=128 copies 16B of V (frag order)
    const bool isK = threadIdx.x < 128;
    const int  i   = threadIdx.x & 127;
    const f16* gsrc = isK ? (kg + (size_t)bh * Ss * HSs + i * 8)
                          : (vg + (size_t)bh * 32768 + i * 8);
    const int koff = (i >> 1) * 24 + (i & 1) * 8;
    const int voff = (i >> 5) * 512 + ((i >> 4) & 1) * 256 + (i & 15) * 8;
    f16x8 sreg = *(const f16x8*)gsrc;

    if (isK) *(f16x8*)&Ks[0][koff] = sreg; else *(f16x8*)&Vf[0][voff] = sreg;
    gsrc += 1024; sreg = *(const f16x8*)gsrc;

    f32x16 acc = {};
    const f32x16 z16 = {};
    float m = -1e30f;

    for (int it = 0; it < Ss / 64; ++it) {
        __syncthreads();
        if (it < Ss / 64 - 1) {
            const int nb = (it + 1) & 1;
            if (isK) *(f16x8*)&Ks[nb][koff] = sreg; else *(f16x8*)&Vf[nb][voff] = sreg;
            gsrc += 1024; sreg = *(const f16x8*)gsrc;   // final prefetch over-reads ws
        }
        const int cb = it & 1;

        // S^T = K x Q^T for key groups 0..31, 32..63
        f16x8 ka0 = *(const f16x8*)&Ks[cb][q31 * 24 + 8 * h];
        f16x8 ka1 = *(const f16x8*)&Ks[cb][(32 + q31) * 24 + 8 * h];
        f32x16 st0 = __builtin_amdgcn_mfma_f32_32x32x16_f16(ka0, qf, z16, 0, 0, 0);
        f32x16 st1 = __builtin_amdgcn_mfma_f32_32x32x16_f16(ka1, qf, z16, 0, 0, 0);

        // max over 64 keys (in-lane tree + one xor32)
        float mx = st0[0];
#pragma unroll
        for (int t = 1; t < 16; ++t) mx = fmaxf(mx, st0[t]);
#pragma unroll
        for (int t = 0; t < 16; ++t) mx = fmaxf(mx, st1[t]);
        mx = fmaxf(mx, __shfl_xor(mx, 32, 64));
        const float mnew = fmaxf(m, mx);
        const float corr = __builtin_amdgcn_exp2f(m - mnew);
#pragma unroll
        for (int r = 0; r < 9; ++r) acc[r] *= corr;   // d<16 regs + l in acc[8]
        m = mnew;

        // p = exp2(s - mnew), pack to f16 P
#pragma unroll
        for (int t = 0; t < 16; ++t) st0[t] = __builtin_amdgcn_exp2f(st0[t] - mnew);
#pragma unroll
        for (int t = 0; t < 16; ++t) st1[t] = __builtin_amdgcn_exp2f(st1[t] - mnew);
        unsigned pw0[8], pw1[8];
#pragma unroll
        for (int r = 0; r < 8; ++r) pw0[r] = pack_rtz(st0[2 * r], st0[2 * r + 1]);
#pragma unroll
        for (int r = 0; r < 8; ++r) pw1[r] = pack_rtz(st1[2 * r], st1[2 * r + 1]);
        f16x8 B1, B2, B3, B4;
        cb_exchange(pw0, h, B1, B2);
        cb_exchange(pw1, h, B3, B4);

        // O^T += V'^T x P^T (ones-row at m=16 accumulates l into acc[8])
        f16x8 va0 = *(const f16x8*)&Vf[cb][0 * 512 + lane * 8];
        f16x8 va1 = *(const f16x8*)&Vf[cb][1 * 512 + lane * 8];
        f16x8 va2 = *(const f16x8*)&Vf[cb][2 * 512 + lane * 8];
        f16x8 va3 = *(const f16x8*)&Vf[cb][3 * 512 + lane * 8];
        acc = __builtin_amdgcn_mfma_f32_32x32x16_f16(va0, B1, acc, 0, 0, 0);
        acc = __builtin_amdgcn_mfma_f32_32x32x16_f16(va1, B2, acc, 0, 0, 0);
        acc = __builtin_amdgcn_mfma_f32_32x32x16_f16(va2, B3, acc, 0, 0, 0);
        acc = __builtin_amdgcn_mfma_f32_32x32x16_f16(va3, B4, acc, 0, 0, 0);
    }

    // l lives in acc[8] of the h=0 half (row 16); h=1 half's acc[8] is 0
    const float l = acc[8] + __shfl_xor(acc[8], 32, 64);
    const float inv = 1.f / l;
    const int b = bh >> 3, head = bh & 7;
    f16* op = og + ((size_t)b * Ss + qbase + q31) * Ee + head * HSs;
    uint2 lo = { pack_rne(acc[0] * inv, acc[1] * inv), pack_rne(acc[2] * inv, acc[3] * inv) };
    uint2 hi = { pack_rne(acc[4] * inv, acc[5] * inv), pack_rne(acc[6] * inv, acc[7] * inv) };
    *(uint2*)(op + 4 * h)     = lo;
    *(uint2*)(op + 8 + 4 * h) = hi;
}

// ---------------------------------------------------------------------------
// Kernel C: output projection. 32-row tiles, grid 512, 4 waves (one channel
// group each). O tile staged via LDS coalesced; Wp f16 (L1-hot); fp32 out.
// ---------------------------------------------------------------------------
__global__ __launch_bounds__(256) void proj_kernel(
    const f16* __restrict__ oh, const f16* __restrict__ wph,
    const float* __restrict__ bp, float* __restrict__ out)
{
    constexpr int LDW = 136;
    __shared__ __align__(16) f16 Os[32 * LDW];    // 8.7 KB
    const int rowbase = blockIdx.x * 32;

    for (int idx = threadIdx.x; idx < 512; idx += 256) {
        const int r = idx >> 4, cp = idx & 15;
        *(f16x8*)&Os[r * LDW + cp * 8] =
            *(const f16x8*)(oh + (size_t)(rowbase + r) * Ee + cp * 8);
    }
    __syncthreads();

    const int wv_ = threadIdx.x >> 6, lane = threadIdx.x & 63;
    const int h = lane >> 5, n31 = lane & 31;

    f16x8 A[8];
#pragma unroll
    for (int t = 0; t < 8; ++t)
        A[t] = *(const f16x8*)&Os[n31 * LDW + 16 * t + 8 * h];

    const int e = wv_ * 32 + n31;
    const f16* wr = wph + (size_t)e * Ee + 8 * h;
    f32x16 acc = {};
#pragma unroll
    for (int t = 0; t < 8; ++t)
        acc = __builtin_amdgcn_mfma_f32_32x32x16_f16(A[t], *(const f16x8*)(wr + 16 * t), acc, 0, 0, 0);

    const float bias = bp[e];
#pragma unroll
    for (int r = 0; r < 16; ++r) {
        const int R = rowbase + (r & 3) + 8 * (r >> 2) + 4 * h;
        out[(size_t)R * Ee + e] = acc[r] + bias;
    }
}

// ---------------------------------------------------------------------------
extern "C" void kernel_launch(void* const* d_in, const int* in_sizes, int n_in,
                              void* d_out, int out_size, void* d_ws, size_t ws_size,
                              hipStream_t stream)
{
    const float* x  = (const float*)d_in[0];
    const float* Wk = (const float*)d_in[1];
    const float* Wq = (const float*)d_in[2];
    const float* Wv = (const float*)d_in[3];
    const float* Wp = (const float*)d_in[4];
    const float* bp = (const float*)d_in[5];
    float* out = (float*)d_out;

    f16* ws = (f16*)d_ws;
    f16* qh = ws;                            // 2M f16
    f16* kh = ws + (size_t)QKVSZ;            // 2M
    f16* vh = ws + (size_t)2 * QKVSZ;        // 2M (frag-swizzled)
    f16* oh = ws + (size_t)3 * QKVSZ;        // 2M (absorbs tail over-reads)
    f16* wh = ws + (size_t)4 * QKVSZ;        // 64K: wq|wk|wv|wp

    prep_w<<<64, 256, 0, stream>>>(Wq, Wk, Wv, Wp, wh);
    qkv_kernel<<<dim3(Bb * Ss / 32, 3), 256, 0, stream>>>(x, wh, qh, kh, vh);
    attn_kernel<<<Bb * Hh * (Ss / 128), 256, 0, stream>>>(qh, kh, vh, oh);
    proj_kernel<<<Bb * Ss / 32, 256, 0, stream>>>(oh, wh + 49152, bp, out);
}

// Round 11
// 144.903 us; speedup vs baseline: 1.1814x; 1.0007x over previous
//
#include <hip/hip_runtime.h>
#include <hip/hip_bf16.h>

// Problem constants
constexpr int Bb  = 8;
constexpr int Ss  = 2048;
constexpr int Ee  = 128;
constexpr int Hh  = 8;
constexpr int HSs = 16;
constexpr int QKVSZ = Bb * Hh * Ss * HSs;  // 2,097,152 elements per tensor

typedef _Float16 f16;
typedef __attribute__((ext_vector_type(8)))  _Float16 f16x8;   // 8 f16 = 4 VGPRs
typedef __attribute__((ext_vector_type(16))) float f32x16;

constexpr float QSCALE = 5.770780163555854f;  // 4 * log2(e); folded into stored k

// RTZ packed fp32x2 -> fp16x2
__device__ __forceinline__ unsigned pack_rtz(float lo, float hi) {
    union { __fp16 __attribute__((ext_vector_type(2))) h; unsigned u; } c;
    c.h = __builtin_amdgcn_cvt_pkrtz(lo, hi);
    return c.u;
}
// RNE pair pack
__device__ __forceinline__ unsigned pack_rne(float lo, float hi) {
    union { __attribute__((ext_vector_type(2))) _Float16 h; unsigned u; } c;
    c.h[0] = (f16)lo; c.h[1] = (f16)hi;
    return c.u;
}

// ---------------------------------------------------------------------------
// prep_w: one-time fp32 -> f16 of all weights. wh = [wq|wk|wv|wp], 16K each.
// ---------------------------------------------------------------------------
__global__ __launch_bounds__(256) void prep_w(
    const float* __restrict__ Wq, const float* __restrict__ Wk,
    const float* __restrict__ Wv, const float* __restrict__ Wp,
    f16* __restrict__ wh)
{
    int i = (blockIdx.x * 256 + threadIdx.x) * 4;
    const float* src = (i < 16384) ? (Wq + i)
                     : (i < 32768) ? (Wk + i - 16384)
                     : (i < 49152) ? (Wv + i - 32768) : (Wp + i - 49152);
    float4 v = *(const float4*)src;
    union { f16 h[4]; uint2 u; } c;
    c.h[0] = (f16)v.x; c.h[1] = (f16)v.y; c.h[2] = (f16)v.z; c.h[3] = (f16)v.w;
    *(uint2*)(wh + i) = c.u;
}

// ---------------------------------------------------------------------------
// Kernel A: Q/K/V projection, all 3 mats fused per block (x staged ONCE).
// Grid 512, 4 waves; wave = one 32-channel group, loops over q,k,v.
// A-frags loaded once; Xs reused as output-transpose buffer per mat.
// k scaled by QSCALE pre-round; v stored frag-swizzled for attn:
//   (s,d) -> bh*32768 + (s>>6)*1024 + ((s>>4)&3)*256 + ((s>>3)&1)*128 + d*8 + (s&7)
// 32x32x16 layouts: A[m=lane&31][k=8h+j], B[k=8h+j][n=lane&31],
// C/D[row=(r&3)+8(r>>2)+4h][col=lane&31].
// ---------------------------------------------------------------------------
__global__ __launch_bounds__(256) void qkv_kernel(
    const float* __restrict__ x, const f16* __restrict__ wh,
    f16* __restrict__ qo, f16* __restrict__ ko, f16* __restrict__ vo)
{
    constexpr int LDW = 136;                      // padded row (f16), b128-aligned
    __shared__ __align__(16) f16 Xs[32 * LDW];    // 8.7 KB; reused per mat

    const int rowbase = blockIdx.x * 32;

    // stage X tile (32 x 128) fp32 -> f16, coalesced float4 reads
    for (int idx = threadIdx.x; idx < 32 * 32; idx += 256) {
        const int r = idx >> 5, cp = idx & 31;
        float4 v = *(const float4*)(x + (size_t)(rowbase + r) * Ee + cp * 4);
        union { f16 h[4]; uint2 u; } c;
        c.h[0] = (f16)v.x; c.h[1] = (f16)v.y; c.h[2] = (f16)v.z; c.h[3] = (f16)v.w;
        *(uint2*)&Xs[r * LDW + cp * 4] = c.u;
    }
    __syncthreads();

    const int wv_ = threadIdx.x >> 6, lane = threadIdx.x & 63;
    const int h = lane >> 5, n31 = lane & 31;

    f16x8 A[8];
#pragma unroll
    for (int t = 0; t < 8; ++t)
        A[t] = *(const f16x8*)&Xs[n31 * LDW + 16 * t + 8 * h];

    const int c = wv_ * 32 + n31;                 // channel 0..127 = head*16+d
    const int b = rowbase >> 11;
    const int s0 = rowbase & 2047;

    for (int mat = 0; mat < 3; ++mat) {
        const f16* wr = wh + mat * 16384 + (size_t)c * Ee + 8 * h;
        f32x16 acc = {};
#pragma unroll
        for (int t = 0; t < 8; ++t)
            acc = __builtin_amdgcn_mfma_f32_32x32x16_f16(A[t], *(const f16x8*)(wr + 16 * t), acc, 0, 0, 0);

        __syncthreads();                          // Xs readers (A or prev copy) done
        const float scale = (mat == 1) ? QSCALE : 1.f;
#pragma unroll
        for (int r = 0; r < 16; ++r) {
            const int row = (r & 3) + 8 * (r >> 2) + 4 * h;
            Xs[row * LDW + c] = (f16)(acc[r] * scale);
        }
        __syncthreads();

        f16* dst = (mat == 0) ? qo : ((mat == 1) ? ko : vo);
        if (mat < 2) {
            for (int i = threadIdx.x; i < 512; i += 256) {
                const int head = i >> 6, rem = i & 63;
                const int s = rem >> 1, dh = rem & 1;
                const int bh = b * Hh + head;
                *(uint4*)(dst + ((size_t)bh * Ss + s0 + s) * HSs + dh * 8) =
                    *(const uint4*)&Xs[s * LDW + head * HSs + dh * 8];
            }
        } else {
            for (int i = threadIdx.x; i < 512; i += 256) {
                const int head = i >> 6, rem = i & 63;
                const int d = rem & 15, ehalf = (rem >> 4) & 1, squart = rem >> 5;
                const int bh = b * Hh + head;
                union { f16 hv[8]; uint4 u; } pkt;
#pragma unroll
                for (int j = 0; j < 8; ++j) {
                    const int ls = squart * 16 + ehalf * 8 + j;
                    pkt.hv[j] = Xs[ls * LDW + head * HSs + d];
                }
                const size_t go = (size_t)bh * 32768 + (s0 >> 6) * 1024
                                + ((((s0 & 32) >> 4)) + squart) * 256 + ehalf * 128 + d * 8;
                *(uint4*)(dst + go) = pkt.u;
            }
        }
    }
}

// ---------------------------------------------------------------------------
// Kernel B: MFMA flash attention. 2 waves/block, 2048 blocks (8 blocks/CU —
// double the resident waves of R10's 1024x4w config). 64-key chunks, dbuf
// staging (each thread copies one K and one V 16B chunk), l via ones-row
// MFMA (acc[8]). Wave owns 32 queries; q = lane&31 lane-local.
// XCD swizzle: 32 q-blocks of each bh land on one XCD.
// ---------------------------------------------------------------------------
__device__ __forceinline__ void cb_exchange(const unsigned* pw, int h,
                                            f16x8& Blo, f16x8& Bhi) {
    unsigned exa = (unsigned)__shfl_xor((int)(h ? pw[0] : pw[2]), 32, 64);
    unsigned exb = (unsigned)__shfl_xor((int)(h ? pw[1] : pw[3]), 32, 64);
    unsigned exc = (unsigned)__shfl_xor((int)(h ? pw[4] : pw[6]), 32, 64);
    unsigned exd = (unsigned)__shfl_xor((int)(h ? pw[5] : pw[7]), 32, 64);
    union { unsigned u[4]; f16x8 v; } B1, B2;
    if (h == 0) {
        B1.u[0] = pw[0]; B1.u[1] = pw[1]; B1.u[2] = exa; B1.u[3] = exb;
        B2.u[0] = pw[4]; B2.u[1] = pw[5]; B2.u[2] = exc; B2.u[3] = exd;
    } else {
        B1.u[0] = exa; B1.u[1] = exb; B1.u[2] = pw[2]; B1.u[3] = pw[3];
        B2.u[0] = exc; B2.u[1] = exd; B2.u[2] = pw[6]; B2.u[3] = pw[7];
    }
    Blo = B1.v; Bhi = B2.v;
}

__global__ __launch_bounds__(128) void attn_kernel(
    const f16* __restrict__ qg, const f16* __restrict__ kg,
    const f16* __restrict__ vg, f16* __restrict__ og)
{
    __shared__ __align__(16) f16 Ks[2][64 * 24];   // dbuf [key][d], 48B rows, 6KB
    __shared__ __align__(16) f16 Vf[2][2048];      // dbuf A-frag order, 8KB

    // XCD-aware decode: 2048 blocks; bh = xcd*8 + (w>>5), qblk = w&31
    const int blk  = blockIdx.x;
    const int w_   = blk >> 3;
    const int bh   = (blk & 7) * 8 + (w_ >> 5);
    const int qblk = w_ & 31;
    const int wv_  = threadIdx.x >> 6;             // 0..1
    const int lane = threadIdx.x & 63;
    const int h    = lane >> 5;
    const int q31  = lane & 31;
    const int qbase = qblk * 64 + wv_ * 32;

    // fill Vf pad rows (m>=16): zeros, EXCEPT m==16 row = ones (l-accumulator)
    for (int i = threadIdx.x; i < 256; i += 128) {
        const int bb = i >> 7, rem = i & 127;
        const int g = rem >> 5, hh = (rem >> 4) & 1, sub = rem & 15;
        const unsigned one2 = 0x3C003C00u;         // two f16 1.0
        uint4 val = (sub == 0) ? (uint4){one2, one2, one2, one2} : (uint4){0, 0, 0, 0};
        *(uint4*)&Vf[bb][g * 512 + hh * 256 + 128 + sub * 8] = val;
    }

    // Q B-frag (QSCALE folded into k)
    const f16x8 qf = *(const f16x8*)(qg + ((size_t)bh * Ss + qbase + q31) * HSs + 8 * h);

    // staging: each of 128 threads copies one K chunk AND one V chunk (16B each)
    const int  i    = threadIdx.x;
    const f16* gk   = kg + (size_t)bh * Ss * HSs + i * 8;
    const f16* gv   = vg + (size_t)bh * 32768 + i * 8;
    const int koff  = (i >> 1) * 24 + (i & 1) * 8;
    const int voff  = (i >> 5) * 512 + ((i >> 4) & 1) * 256 + (i & 15) * 8;
    f16x8 kreg = *(const f16x8*)gk;
    f16x8 vreg = *(const f16x8*)gv;

    *(f16x8*)&Ks[0][koff] = kreg;
    *(f16x8*)&Vf[0][voff] = vreg;
    gk += 1024; gv += 1024;
    kreg = *(const f16x8*)gk; vreg = *(const f16x8*)gv;

    f32x16 acc = {};
    const f32x16 z16 = {};
    float m = -1e30f;

    for (int it = 0; it < Ss / 64; ++it) {
        __syncthreads();
        if (it < Ss / 64 - 1) {
            const int nb = (it + 1) & 1;
            *(f16x8*)&Ks[nb][koff] = kreg;
            *(f16x8*)&Vf[nb][voff] = vreg;
            gk += 1024; gv += 1024;
            kreg = *(const f16x8*)gk;   // final prefetch over-reads ws (unused)
            vreg = *(const f16x8*)gv;
        }
        const int cb = it & 1;

        // S^T = K x Q^T for key groups 0..31, 32..63
        f16x8 ka0 = *(const f16x8*)&Ks[cb][q31 * 24 + 8 * h];
        f16x8 ka1 = *(const f16x8*)&Ks[cb][(32 + q31) * 24 + 8 * h];
        f32x16 st0 = __builtin_amdgcn_mfma_f32_32x32x16_f16(ka0, qf, z16, 0, 0, 0);
        f32x16 st1 = __builtin_amdgcn_mfma_f32_32x32x16_f16(ka1, qf, z16, 0, 0, 0);

        // max over 64 keys (in-lane tree + one xor32)
        float mx = st0[0];
#pragma unroll
        for (int t = 1; t < 16; ++t) mx = fmaxf(mx, st0[t]);
#pragma unroll
        for (int t = 0; t < 16; ++t) mx = fmaxf(mx, st1[t]);
        mx = fmaxf(mx, __shfl_xor(mx, 32, 64));
        const float mnew = fmaxf(m, mx);
        const float corr = __builtin_amdgcn_exp2f(m - mnew);
#pragma unroll
        for (int r = 0; r < 9; ++r) acc[r] *= corr;   // d<16 regs + l in acc[8]
        m = mnew;

        // p = exp2(s - mnew), pack to f16 P
#pragma unroll
        for (int t = 0; t < 16; ++t) st0[t] = __builtin_amdgcn_exp2f(st0[t] - mnew);
#pragma unroll
        for (int t = 0; t < 16; ++t) st1[t] = __builtin_amdgcn_exp2f(st1[t] - mnew);
        unsigned pw0[8], pw1[8];
#pragma unroll
        for (int r = 0; r < 8; ++r) pw0[r] = pack_rtz(st0[2 * r], st0[2 * r + 1]);
#pragma unroll
        for (int r = 0; r < 8; ++r) pw1[r] = pack_rtz(st1[2 * r], st1[2 * r + 1]);
        f16x8 B1, B2, B3, B4;
        cb_exchange(pw0, h, B1, B2);
        cb_exchange(pw1, h, B3, B4);

        // O^T += V'^T x P^T (ones-row at m=16 accumulates l into acc[8])
        f16x8 va0 = *(const f16x8*)&Vf[cb][0 * 512 + lane * 8];
        f16x8 va1 = *(const f16x8*)&Vf[cb][1 * 512 + lane * 8];
        f16x8 va2 = *(const f16x8*)&Vf[cb][2 * 512 + lane * 8];
        f16x8 va3 = *(const f16x8*)&Vf[cb][3 * 512 + lane * 8];
        acc = __builtin_amdgcn_mfma_f32_32x32x16_f16(va0, B1, acc, 0, 0, 0);
        acc = __builtin_amdgcn_mfma_f32_32x32x16_f16(va1, B2, acc, 0, 0, 0);
        acc = __builtin_amdgcn_mfma_f32_32x32x16_f16(va2, B3, acc, 0, 0, 0);
        acc = __builtin_amdgcn_mfma_f32_32x32x16_f16(va3, B4, acc, 0, 0, 0);
    }

    // l lives in acc[8] of the h=0 half (row 16); h=1 half's acc[8] is 0
    const float l = acc[8] + __shfl_xor(acc[8], 32, 64);
    const float inv = 1.f / l;
    const int b = bh >> 3, head = bh & 7;
    f16* op = og + ((size_t)b * Ss + qbase + q31) * Ee + head * HSs;
    uint2 lo = { pack_rne(acc[0] * inv, acc[1] * inv), pack_rne(acc[2] * inv, acc[3] * inv) };
    uint2 hi = { pack_rne(acc[4] * inv, acc[5] * inv), pack_rne(acc[6] * inv, acc[7] * inv) };
    *(uint2*)(op + 4 * h)     = lo;
    *(uint2*)(op + 8 + 4 * h) = hi;
}

// ---------------------------------------------------------------------------
// Kernel C: output projection. 32-row tiles, grid 512, 4 waves (one channel
// group each). O tile staged via LDS coalesced; Wp f16 (L1-hot); fp32 out.
// ---------------------------------------------------------------------------
__global__ __launch_bounds__(256) void proj_kernel(
    const f16* __restrict__ oh, const f16* __restrict__ wph,
    const float* __restrict__ bp, float* __restrict__ out)
{
    constexpr int LDW = 136;
    __shared__ __align__(16) f16 Os[32 * LDW];    // 8.7 KB
    const int rowbase = blockIdx.x * 32;

    for (int idx = threadIdx.x; idx < 512; idx += 256) {
        const int r = idx >> 4, cp = idx & 15;
        *(f16x8*)&Os[r * LDW + cp * 8] =
            *(const f16x8*)(oh + (size_t)(rowbase + r) * Ee + cp * 8);
    }
    __syncthreads();

    const int wv_ = threadIdx.x >> 6, lane = threadIdx.x & 63;
    const int h = lane >> 5, n31 = lane & 31;

    f16x8 A[8];
#pragma unroll
    for (int t = 0; t < 8; ++t)
        A[t] = *(const f16x8*)&Os[n31 * LDW + 16 * t + 8 * h];

    const int e = wv_ * 32 + n31;
    const f16* wr = wph + (size_t)e * Ee + 8 * h;
    f32x16 acc = {};
#pragma unroll
    for (int t = 0; t < 8; ++t)
        acc = __builtin_amdgcn_mfma_f32_32x32x16_f16(A[t], *(const f16x8*)(wr + 16 * t), acc, 0, 0, 0);

    const float bias = bp[e];
#pragma unroll
    for (int r = 0; r < 16; ++r) {
        const int R = rowbase + (r & 3) + 8 * (r >> 2) + 4 * h;
        out[(size_t)R * Ee + e] = acc[r] + bias;
    }
}

// ---------------------------------------------------------------------------
extern "C" void kernel_launch(void* const* d_in, const int* in_sizes, int n_in,
                              void* d_out, int out_size, void* d_ws, size_t ws_size,
                              hipStream_t stream)
{
    const float* x  = (const float*)d_in[0];
    const float* Wk = (const float*)d_in[1];
    const float* Wq = (const float*)d_in[2];
    const float* Wv = (const float*)d_in[3];
    const float* Wp = (const float*)d_in[4];
    const float* bp = (const float*)d_in[5];
    float* out = (float*)d_out;

    f16* ws = (f16*)d_ws;
    f16* qh = ws;                            // 2M f16
    f16* kh = ws + (size_t)QKVSZ;            // 2M
    f16* vh = ws + (size_t)2 * QKVSZ;        // 2M (frag-swizzled)
    f16* oh = ws + (size_t)3 * QKVSZ;        // 2M (absorbs tail over-reads)
    f16* wh = ws + (size_t)4 * QKVSZ;        // 64K: wq|wk|wv|wp

    prep_w<<<64, 256, 0, stream>>>(Wq, Wk, Wv, Wp, wh);
    qkv_kernel<<<Bb * Ss / 32, 256, 0, stream>>>(x, wh, qh, kh, vh);
    attn_kernel<<<Bb * Hh * (Ss / 64), 128, 0, stream>>>(qh, kh, vh, oh);
    proj_kernel<<<Bb * Ss / 32, 256, 0, stream>>>(oh, wh + 49152, bp, out);
}

// Round 12
// 137.631 us; speedup vs baseline: 1.2439x; 1.0528x over previous
//
#include <hip/hip_runtime.h>
#include <hip/hip_bf16.h>

// Problem constants
constexpr int Bb  = 8;
constexpr int Ss  = 2048;
constexpr int Ee  = 128;
constexpr int Hh  = 8;
constexpr int HSs = 16;
constexpr int QKVSZ = Bb * Hh * Ss * HSs;  // 2,097,152 elements per tensor

typedef _Float16 f16;
typedef __attribute__((ext_vector_type(8)))  _Float16 f16x8;   // 8 f16 = 4 VGPRs
typedef __attribute__((ext_vector_type(16))) float f32x16;

constexpr float QSCALE = 5.770780163555854f;  // 4 * log2(e); folded into stored k

// RTZ packed fp32x2 -> fp16x2
__device__ __forceinline__ unsigned pack_rtz(float lo, float hi) {
    union { __fp16 __attribute__((ext_vector_type(2))) h; unsigned u; } c;
    c.h = __builtin_amdgcn_cvt_pkrtz(lo, hi);
    return c.u;
}
// RNE pair pack
__device__ __forceinline__ unsigned pack_rne(float lo, float hi) {
    union { __attribute__((ext_vector_type(2))) _Float16 h; unsigned u; } c;
    c.h[0] = (f16)lo; c.h[1] = (f16)hi;
    return c.u;
}

// ---------------------------------------------------------------------------
// prep_w: one-time fp32 -> f16 of all weights. wh = [wq|wk|wv|wp], 16K each.
// ---------------------------------------------------------------------------
__global__ __launch_bounds__(256) void prep_w(
    const float* __restrict__ Wq, const float* __restrict__ Wk,
    const float* __restrict__ Wv, const float* __restrict__ Wp,
    f16* __restrict__ wh)
{
    int i = (blockIdx.x * 256 + threadIdx.x) * 4;
    const float* src = (i < 16384) ? (Wq + i)
                     : (i < 32768) ? (Wk + i - 16384)
                     : (i < 49152) ? (Wv + i - 32768) : (Wp + i - 49152);
    float4 v = *(const float4*)src;
    union { f16 h[4]; uint2 u; } c;
    c.h[0] = (f16)v.x; c.h[1] = (f16)v.y; c.h[2] = (f16)v.z; c.h[3] = (f16)v.w;
    *(uint2*)(wh + i) = c.u;
}

// ---------------------------------------------------------------------------
// Kernel A: Q/K/V projection, SINGLE-PHASE. Grid (512, 3), 4 waves.
// Stage X fp32->f16 via LDS (1 barrier), A-frags from LDS, 8 MFMA, direct
// global stores. k scaled by QSCALE. v written in GLOBAL A-FRAG ORDER with
// pad rows (m=16 -> 1.0 for MFMA-l trick, m>16 -> 0) so attn needs no LDS:
//   V elem (s,d): vh[bh*65536 + (s>>6)*2048 + ((s>>4)&3)*512
//                    + (d + 32*((s>>3)&1))*8 + (s&7)]
// 32x32x16 layouts: A[m=lane&31][k=8h+j], B[k=8h+j][n=lane&31],
// C/D[row=(r&3)+8(r>>2)+4h][col=lane&31].
// ---------------------------------------------------------------------------
__global__ __launch_bounds__(256) void qkv_kernel(
    const float* __restrict__ x, const f16* __restrict__ wh,
    f16* __restrict__ qo, f16* __restrict__ ko, f16* __restrict__ vo)
{
    constexpr int LDW = 136;                      // padded row (f16), b128-aligned
    __shared__ __align__(16) f16 Xs[32 * LDW];    // 8.7 KB

    const int mat = blockIdx.y;                   // 0=q,1=k,2=v
    const int rowbase = blockIdx.x * 32;

    // stage X tile (32 x 128) fp32 -> f16, coalesced float4 reads
    for (int idx = threadIdx.x; idx < 32 * 32; idx += 256) {
        const int r = idx >> 5, cp = idx & 31;
        float4 v = *(const float4*)(x + (size_t)(rowbase + r) * Ee + cp * 4);
        union { f16 h[4]; uint2 u; } c;
        c.h[0] = (f16)v.x; c.h[1] = (f16)v.y; c.h[2] = (f16)v.z; c.h[3] = (f16)v.w;
        *(uint2*)&Xs[r * LDW + cp * 4] = c.u;
    }
    __syncthreads();

    const int wv_ = threadIdx.x >> 6, lane = threadIdx.x & 63;
    const int h = lane >> 5, n31 = lane & 31;

    f16x8 A[8];
#pragma unroll
    for (int t = 0; t < 8; ++t)
        A[t] = *(const f16x8*)&Xs[n31 * LDW + 16 * t + 8 * h];

    const int c = wv_ * 32 + n31;                 // channel 0..127 = head*16+d
    const f16* wr = wh + mat * 16384 + (size_t)c * Ee + 8 * h;
    f32x16 acc = {};
#pragma unroll
    for (int t = 0; t < 8; ++t)
        acc = __builtin_amdgcn_mfma_f32_32x32x16_f16(A[t], *(const f16x8*)(wr + 16 * t), acc, 0, 0, 0);

    const int b = rowbase >> 11;
    const int s0 = rowbase & 2047;
    const int head = c >> 4, d = c & 15;
    const int bh = b * Hh + head;

    if (mat < 2) {
        f16* dst = (mat == 0) ? qo : ko;
        const float scale = (mat == 1) ? QSCALE : 1.f;
#pragma unroll
        for (int r = 0; r < 16; ++r) {
            const int s = s0 + (r & 3) + 8 * (r >> 2) + 4 * h;
            dst[((size_t)bh * Ss + s) * HSs + d] = (f16)(acc[r] * scale);
        }
    } else {
        const int it = s0 >> 6, g0 = (s0 >> 4) & 3;
        f16* vb = vo + (size_t)bh * 65536 + it * 2048;
#pragma unroll
        for (int rq = 0; rq < 4; ++rq) {
            union { f16 hv[4]; uint2 u; } pk4;
#pragma unroll
            for (int i = 0; i < 4; ++i) pk4.hv[i] = (f16)acc[4 * rq + i];
            *(uint2*)(vb + (g0 + (rq >> 1)) * 512 + (d + 32 * (rq & 1)) * 8 + 4 * h) = pk4.u;
        }
        // pad rows m=16..31 for this block's two 16-key groups, all 8 heads:
        // m==16 -> 1.0 (l-accumulator row), else 0
        for (int i = threadIdx.x; i < 512; i += 256) {
            const int gp = i >> 8, hd = (i >> 5) & 7, cc = i & 31;
            const int lanep = (cc < 16) ? 16 + cc : 32 + cc;
            const unsigned one2 = 0x3C003C00u;
            uint4 val = ((cc & 15) == 0) ? (uint4){one2, one2, one2, one2}
                                         : (uint4){0, 0, 0, 0};
            *(uint4*)(vo + (size_t)(b * Hh + hd) * 65536 + it * 2048
                      + (g0 + gp) * 512 + lanep * 8) = val;
        }
    }
}

// ---------------------------------------------------------------------------
// Kernel B: MFMA flash attention, NO LDS, NO BARRIERS. 4096 blocks x 1 wave;
// wave owns 32 queries, streams 64-key chunks. All MFMA operands are direct
// 16B/lane global loads (K row-major, V pre-swizzled to A-frag order with
// ones-row for l). Register prefetch of next chunk. Softmax lane-local
// (q = lane&31); P^T C->B relayout via shfl_xor 32.
// XCD swizzle: bh = (blk&7)*8 + blk>>9 -> each bh's 64 blocks on one XCD.
// ---------------------------------------------------------------------------
__device__ __forceinline__ void cb_exchange(const unsigned* pw, int h,
                                            f16x8& Blo, f16x8& Bhi) {
    unsigned exa = (unsigned)__shfl_xor((int)(h ? pw[0] : pw[2]), 32, 64);
    unsigned exb = (unsigned)__shfl_xor((int)(h ? pw[1] : pw[3]), 32, 64);
    unsigned exc = (unsigned)__shfl_xor((int)(h ? pw[4] : pw[6]), 32, 64);
    unsigned exd = (unsigned)__shfl_xor((int)(h ? pw[5] : pw[7]), 32, 64);
    union { unsigned u[4]; f16x8 v; } B1, B2;
    if (h == 0) {
        B1.u[0] = pw[0]; B1.u[1] = pw[1]; B1.u[2] = exa; B1.u[3] = exb;
        B2.u[0] = pw[4]; B2.u[1] = pw[5]; B2.u[2] = exc; B2.u[3] = exd;
    } else {
        B1.u[0] = exa; B1.u[1] = exb; B1.u[2] = pw[2]; B1.u[3] = pw[3];
        B2.u[0] = exc; B2.u[1] = exd; B2.u[2] = pw[6]; B2.u[3] = pw[7];
    }
    Blo = B1.v; Bhi = B2.v;
}

__global__ __launch_bounds__(64, 4) void attn_kernel(
    const f16* __restrict__ qg, const f16* __restrict__ kg,
    const f16* __restrict__ vg, f16* __restrict__ og)
{
    const int blk  = blockIdx.x;                   // 4096
    const int bh   = (blk & 7) * 8 + (blk >> 9);   // XCD-local bh groups
    const int qblk = (blk >> 3) & 63;
    const int lane = threadIdx.x;
    const int h    = lane >> 5;
    const int q31  = lane & 31;
    const int qbase = qblk * 32;

    // Q B-frag (QSCALE folded into k)
    const f16x8 qf = *(const f16x8*)(qg + ((size_t)bh * Ss + qbase + q31) * HSs + 8 * h);

    // per-lane streaming pointers (16B/lane contiguous, coalesced per wave)
    const f16* pk = kg + (size_t)bh * Ss * HSs + q31 * 16 + 8 * h;
    const f16* pv = vg + (size_t)bh * 65536 + lane * 8;

    // current-chunk operands
    f16x8 ka0 = *(const f16x8*)pk;
    f16x8 ka1 = *(const f16x8*)(pk + 512);
    f16x8 va0 = *(const f16x8*)(pv);
    f16x8 va1 = *(const f16x8*)(pv + 512);
    f16x8 va2 = *(const f16x8*)(pv + 1024);
    f16x8 va3 = *(const f16x8*)(pv + 1536);

    f32x16 acc = {};
    const f32x16 z16 = {};
    float m = -1e30f;

    for (int it = 0; it < Ss / 64; ++it) {
        // prefetch next chunk into separate regs (no consumer until rotate)
        f16x8 nk0, nk1, nv0, nv1, nv2, nv3;
        if (it < Ss / 64 - 1) {
            pk += 1024; pv += 2048;
            nk0 = *(const f16x8*)pk;
            nk1 = *(const f16x8*)(pk + 512);
            nv0 = *(const f16x8*)(pv);
            nv1 = *(const f16x8*)(pv + 512);
            nv2 = *(const f16x8*)(pv + 1024);
            nv3 = *(const f16x8*)(pv + 1536);
        }

        // S^T = K x Q^T for key groups 0..31, 32..63
        f32x16 st0 = __builtin_amdgcn_mfma_f32_32x32x16_f16(ka0, qf, z16, 0, 0, 0);
        f32x16 st1 = __builtin_amdgcn_mfma_f32_32x32x16_f16(ka1, qf, z16, 0, 0, 0);

        // max over 64 keys (in-lane tree + one xor32)
        float mx = st0[0];
#pragma unroll
        for (int t = 1; t < 16; ++t) mx = fmaxf(mx, st0[t]);
#pragma unroll
        for (int t = 0; t < 16; ++t) mx = fmaxf(mx, st1[t]);
        mx = fmaxf(mx, __shfl_xor(mx, 32, 64));
        const float mnew = fmaxf(m, mx);
        const float corr = __builtin_amdgcn_exp2f(m - mnew);
#pragma unroll
        for (int r = 0; r < 9; ++r) acc[r] *= corr;   // d<16 regs + l in acc[8]
        m = mnew;

        // p = exp2(s - mnew), pack to f16 P
#pragma unroll
        for (int t = 0; t < 16; ++t) st0[t] = __builtin_amdgcn_exp2f(st0[t] - mnew);
#pragma unroll
        for (int t = 0; t < 16; ++t) st1[t] = __builtin_amdgcn_exp2f(st1[t] - mnew);
        unsigned pw0[8], pw1[8];
#pragma unroll
        for (int r = 0; r < 8; ++r) pw0[r] = pack_rtz(st0[2 * r], st0[2 * r + 1]);
#pragma unroll
        for (int r = 0; r < 8; ++r) pw1[r] = pack_rtz(st1[2 * r], st1[2 * r + 1]);
        f16x8 B1, B2, B3, B4;
        cb_exchange(pw0, h, B1, B2);
        cb_exchange(pw1, h, B3, B4);

        // O^T += V'^T x P^T (ones-row at m=16 accumulates l into acc[8])
        acc = __builtin_amdgcn_mfma_f32_32x32x16_f16(va0, B1, acc, 0, 0, 0);
        acc = __builtin_amdgcn_mfma_f32_32x32x16_f16(va1, B2, acc, 0, 0, 0);
        acc = __builtin_amdgcn_mfma_f32_32x32x16_f16(va2, B3, acc, 0, 0, 0);
        acc = __builtin_amdgcn_mfma_f32_32x32x16_f16(va3, B4, acc, 0, 0, 0);

        // rotate prefetched regs in
        ka0 = nk0; ka1 = nk1;
        va0 = nv0; va1 = nv1; va2 = nv2; va3 = nv3;
    }

    // l lives in acc[8] of the h=0 half (row 16); h=1 half's acc[8] is 0
    const float l = acc[8] + __shfl_xor(acc[8], 32, 64);
    const float inv = 1.f / l;
    const int b = bh >> 3, head = bh & 7;
    f16* op = og + ((size_t)b * Ss + qbase + q31) * Ee + head * HSs;
    uint2 lo = { pack_rne(acc[0] * inv, acc[1] * inv), pack_rne(acc[2] * inv, acc[3] * inv) };
    uint2 hi = { pack_rne(acc[4] * inv, acc[5] * inv), pack_rne(acc[6] * inv, acc[7] * inv) };
    *(uint2*)(op + 4 * h)     = lo;
    *(uint2*)(op + 8 + 4 * h) = hi;
}

// ---------------------------------------------------------------------------
// Kernel C: output projection. 32-row tiles, grid 512, 4 waves (one channel
// group each). O tile staged via LDS coalesced; Wp f16 (L1-hot); fp32 out.
// ---------------------------------------------------------------------------
__global__ __launch_bounds__(256) void proj_kernel(
    const f16* __restrict__ oh, const f16* __restrict__ wph,
    const float* __restrict__ bp, float* __restrict__ out)
{
    constexpr int LDW = 136;
    __shared__ __align__(16) f16 Os[32 * LDW];    // 8.7 KB
    const int rowbase = blockIdx.x * 32;

    for (int idx = threadIdx.x; idx < 512; idx += 256) {
        const int r = idx >> 4, cp = idx & 15;
        *(f16x8*)&Os[r * LDW + cp * 8] =
            *(const f16x8*)(oh + (size_t)(rowbase + r) * Ee + cp * 8);
    }
    __syncthreads();

    const int wv_ = threadIdx.x >> 6, lane = threadIdx.x & 63;
    const int h = lane >> 5, n31 = lane & 31;

    f16x8 A[8];
#pragma unroll
    for (int t = 0; t < 8; ++t)
        A[t] = *(const f16x8*)&Os[n31 * LDW + 16 * t + 8 * h];

    const int e = wv_ * 32 + n31;
    const f16* wr = wph + (size_t)e * Ee + 8 * h;
    f32x16 acc = {};
#pragma unroll
    for (int t = 0; t < 8; ++t)
        acc = __builtin_amdgcn_mfma_f32_32x32x16_f16(A[t], *(const f16x8*)(wr + 16 * t), acc, 0, 0, 0);

    const float bias = bp[e];
#pragma unroll
    for (int r = 0; r < 16; ++r) {
        const int R = rowbase + (r & 3) + 8 * (r >> 2) + 4 * h;
        out[(size_t)R * Ee + e] = acc[r] + bias;
    }
}

// ---------------------------------------------------------------------------
extern "C" void kernel_launch(void* const* d_in, const int* in_sizes, int n_in,
                              void* d_out, int out_size, void* d_ws, size_t ws_size,
                              hipStream_t stream)
{
    const float* x  = (const float*)d_in[0];
    const float* Wk = (const float*)d_in[1];
    const float* Wq = (const float*)d_in[2];
    const float* Wv = (const float*)d_in[3];
    const float* Wp = (const float*)d_in[4];
    const float* bp = (const float*)d_in[5];
    float* out = (float*)d_out;

    f16* ws = (f16*)d_ws;
    f16* qh = ws;                            // 2M halves
    f16* kh = ws + (size_t)QKVSZ;            // 2M
    f16* vh = ws + (size_t)2 * QKVSZ;        // 4M (A-frag order + pad rows)
    f16* oh = ws + (size_t)4 * QKVSZ;        // 2M
    f16* wh = ws + (size_t)5 * QKVSZ;        // 64K: wq|wk|wv|wp

    prep_w<<<64, 256, 0, stream>>>(Wq, Wk, Wv, Wp, wh);
    qkv_kernel<<<dim3(Bb * Ss / 32, 3), 256, 0, stream>>>(x, wh, qh, kh, vh);
    attn_kernel<<<Bb * Hh * (Ss / 32), 64, 0, stream>>>(qh, kh, vh, oh);
    proj_kernel<<<Bb * Ss / 32, 256, 0, stream>>>(oh, wh + 49152, bp, out);
}